// Round 5
// baseline (205.865 us; speedup 1.0000x reference)
//
#include <hip/hip_runtime.h>

// irreps: x1 = 128x0e + 128x1o (512), x2 = 1x0e + 1x1o (4), w = 5*128 (640)
// out = 128x0e + 128x1o (512). All fp32. Memory-bound streaming op.
//
// Per edge z, channel u:
//   s = x1[z,u]; v = x1[z,128+3u .. +3); a = x2[z,0]; b = x2[z,1..4)
//   out[z,u]        = s*a*w0[u] + (1/sqrt3)*(v.b)*w3[u]
//   out[z,128+3u+k] = (1/sqrt3)*s*w1[u]*b[k] + (1/sqrt3)*a*w2[u]*v[k]
//                   + (1/sqrt6)*w4[u]*(v x b)[k]
//
// R5 structure: PERSISTENT + PIPELINED. 32 threads per edge (4 channels each,
// all accesses aligned 16B). Each block owns 64 contiguous edges; each thread
// runs 8 iterations with an explicit two-tile (A/B) software pipeline:
// issue tile i+1's 10 loads, then compute+store tile i. This forces the RA
// to keep ~80 load-dest VGPRs live (R1/R4 allocated only 32-36 and
// serialized the loads; one-shot waves ate full loaded latency once each).

typedef float f32x4 __attribute__((ext_vector_type(4)));

struct Tile {
    f32x4 x2v, s4, va, vb, vc, w0, w1, w2, w3, w4;
};

__device__ __forceinline__ void load_tile(Tile& T,
                                          const float* __restrict__ x1,
                                          const float* __restrict__ x2,
                                          const float* __restrict__ w,
                                          int z, int g)
{
    const float* x1row = x1 + (size_t)z * 512;
    const float* wrow  = w  + (size_t)z * 640;
    T.x2v = *reinterpret_cast<const f32x4*>(x2 + (size_t)z * 4);
    T.s4  = *reinterpret_cast<const f32x4*>(x1row + 4 * g);
    T.va  = *reinterpret_cast<const f32x4*>(x1row + 128 + 12 * g);
    T.vb  = *reinterpret_cast<const f32x4*>(x1row + 128 + 12 * g + 4);
    T.vc  = *reinterpret_cast<const f32x4*>(x1row + 128 + 12 * g + 8);
    T.w0  = *reinterpret_cast<const f32x4*>(wrow +   0 + 4 * g);
    T.w1  = *reinterpret_cast<const f32x4*>(wrow + 128 + 4 * g);
    T.w2  = *reinterpret_cast<const f32x4*>(wrow + 256 + 4 * g);
    T.w3  = *reinterpret_cast<const f32x4*>(wrow + 384 + 4 * g);
    T.w4  = *reinterpret_cast<const f32x4*>(wrow + 512 + 4 * g);
}

__device__ __forceinline__ void process_tile(const Tile& T,
                                             float* __restrict__ out,
                                             int z, int g)
{
    constexpr float inv_sqrt3 = 0.57735026918962576f;
    constexpr float inv_sqrt6 = 0.40824829046386302f;

    float* outrow = out + (size_t)z * 512;

    const float a  = T.x2v.x;
    const float bx = T.x2v.y, by = T.x2v.z, bz = T.x2v.w;

    const float s[4]   = {T.s4.x, T.s4.y, T.s4.z, T.s4.w};
    const float vv[12] = {T.va.x, T.va.y, T.va.z, T.va.w,
                          T.vb.x, T.vb.y, T.vb.z, T.vb.w,
                          T.vc.x, T.vc.y, T.vc.z, T.vc.w};
    const float W0[4]  = {T.w0.x, T.w0.y, T.w0.z, T.w0.w};
    const float W1[4]  = {T.w1.x, T.w1.y, T.w1.z, T.w1.w};
    const float W2[4]  = {T.w2.x, T.w2.y, T.w2.z, T.w2.w};
    const float W3[4]  = {T.w3.x, T.w3.y, T.w3.z, T.w3.w};
    const float W4[4]  = {T.w4.x, T.w4.y, T.w4.z, T.w4.w};

    float os[4];
    float ov[12];
#pragma unroll
    for (int c = 0; c < 4; ++c) {
        const float vx = vv[3 * c + 0];
        const float vy = vv[3 * c + 1];
        const float vz = vv[3 * c + 2];
        const float dot = vx * bx + vy * by + vz * bz;
        os[c] = s[c] * a * W0[c] + inv_sqrt3 * dot * W3[c];

        const float cx = vy * bz - vz * by;   // v x b
        const float cy = vz * bx - vx * bz;
        const float cz = vx * by - vy * bx;

        const float t1 = inv_sqrt3 * s[c] * W1[c];
        const float t2 = inv_sqrt3 * a   * W2[c];
        const float t4 = inv_sqrt6 * W4[c];
        ov[3 * c + 0] = t1 * bx + t2 * vx + t4 * cx;
        ov[3 * c + 1] = t1 * by + t2 * vy + t4 * cy;
        ov[3 * c + 2] = t1 * bz + t2 * vz + t4 * cz;
    }

    f32x4 o0 = {os[0], os[1], os[2], os[3]};
    f32x4 o1 = {ov[0], ov[1], ov[2], ov[3]};
    f32x4 o2 = {ov[4], ov[5], ov[6], ov[7]};
    f32x4 o3 = {ov[8], ov[9], ov[10], ov[11]};
    *reinterpret_cast<f32x4*>(outrow + 4 * g)            = o0;
    *reinterpret_cast<f32x4*>(outrow + 128 + 12 * g)     = o1;
    *reinterpret_cast<f32x4*>(outrow + 128 + 12 * g + 4) = o2;
    *reinterpret_cast<f32x4*>(outrow + 128 + 12 * g + 8) = o3;
}

// 256 threads, 8 edges per iteration, 8 iterations -> 64 edges per block.
#define EDGES_PER_ITER 8
#define ITERS 8

__global__ __launch_bounds__(256) void tp_uvu_kernel(
    const float* __restrict__ x1,
    const float* __restrict__ x2,
    const float* __restrict__ w,
    float* __restrict__ out,
    int n_edges)
{
    const int g    = threadIdx.x & 31;
    const int eoff = threadIdx.x >> 5;               // 0..7
    const int base = blockIdx.x * (EDGES_PER_ITER * ITERS);
    const int z0   = base + eoff;
    const int lim  = min(n_edges, base + EDGES_PER_ITER * ITERS);

    Tile A, B;
    if (z0 < lim) load_tile(A, x1, x2, w, z0, g);

    // 4 double-steps = 8 iterations, fully static A/B rotation.
#pragma unroll
    for (int i = 0; i < 4; ++i) {
        const int zA = z0 + 2 * EDGES_PER_ITER * i;
        const int zB = zA + EDGES_PER_ITER;
        const int zA2 = zA + 2 * EDGES_PER_ITER;

        if (zB < lim) load_tile(B, x1, x2, w, zB, g);   // prefetch
        __builtin_amdgcn_sched_barrier(0);              // pin: loads issue first
        if (zA < lim) process_tile(A, out, zA, g);      // compute+store prev

        if (zA2 < lim) load_tile(A, x1, x2, w, zA2, g); // prefetch
        __builtin_amdgcn_sched_barrier(0);
        if (zB < lim) process_tile(B, out, zB, g);
    }
}

extern "C" void kernel_launch(void* const* d_in, const int* in_sizes, int n_in,
                              void* d_out, int out_size, void* d_ws, size_t ws_size,
                              hipStream_t stream) {
    const float* x1 = (const float*)d_in[0];
    const float* x2 = (const float*)d_in[1];
    const float* w  = (const float*)d_in[2];
    float* out = (float*)d_out;

    const int n_edges = in_sizes[0] / 512;
    const int edges_per_block = EDGES_PER_ITER * ITERS;      // 64
    const int grid = (n_edges + edges_per_block - 1) / edges_per_block;

    tp_uvu_kernel<<<grid, 256, 0, stream>>>(x1, x2, w, out, n_edges);
}

// Round 6
// 159.942 us; speedup vs baseline: 1.2871x; 1.2871x over previous
//
#include <hip/hip_runtime.h>

// irreps: x1 = 128x0e + 128x1o (512), x2 = 1x0e + 1x1o (4), w = 5*128 (640)
// out = 128x0e + 128x1o (512). All fp32. Memory-bound streaming op.
//
// Per edge z, channel u:
//   s = x1[z,u]; v = x1[z,128+3u .. +3); a = x2[z,0]; b = x2[z,1..4)
//   out[z,u]        = s*a*w0[u] + (1/sqrt3)*(v.b)*w3[u]
//   out[z,128+3u+k] = (1/sqrt3)*s*w1[u]*b[k] + (1/sqrt3)*a*w2[u]*v[k]
//                   + (1/sqrt6)*w4[u]*(v x b)[k]
//
// R6: fix the strided vector streams. In R4, va/vb/vc loads and o1..o3
// stores were 16B accesses at 48B lane stride -> each instruction touches
// 3KB/48 cache lines for 1/3 of the bytes (~3x L1 transaction work on 6 of
// 14 vmem insts). Here the 3KB vector block per edge goes through LDS:
//   in : 3 coalesced dwordx4 global loads -> ds_write contiguous ->
//        ds_read_b128 at 48B stride (bank 3g%32, 3 coprime 32: ~conflict-free)
//   out: ds_write at 48B stride -> coalesced read-back -> contiguous stores.
// Wave-local staging: each 32-lane group has its own 384-float buffer and is
// lockstep, so NO __syncthreads anywhere. Scalar/weight streams were already
// contiguous and stay direct.

typedef float f32x4 __attribute__((ext_vector_type(4)));

__global__ __launch_bounds__(256) void tp_uvu_kernel(
    const float* __restrict__ x1,
    const float* __restrict__ x2,
    const float* __restrict__ w,
    float* __restrict__ out,
    int n_edges)
{
    __shared__ __align__(16) float lds[8][384];   // one 1.5KB buffer per 32-lane group

    const int tid = blockIdx.x * blockDim.x + threadIdx.x;
    const int z   = tid >> 5;            // edge index (32 threads per edge)
    const int g   = tid & 31;            // channel group: channels 4g..4g+3
    const int grp = threadIdx.x >> 5;    // LDS buffer index (0..7)
    if (z >= n_edges) return;

    constexpr float inv_sqrt3 = 0.57735026918962576f;
    constexpr float inv_sqrt6 = 0.40824829046386302f;

    const float* x1row  = x1  + (size_t)z * 512;
    const float* vbase  = x1row + 128;
    const float* wrow   = w   + (size_t)z * 640;
    float*       outrow = out + (size_t)z * 512;
    float*       buf    = lds[grp];

    // ---- global load phase: all contiguous, all issued before any use ----
    const f32x4 sv0 = *reinterpret_cast<const f32x4*>(vbase + 4 * g);        // vec stage
    const f32x4 sv1 = *reinterpret_cast<const f32x4*>(vbase + 4 * (g + 32));
    const f32x4 sv2 = *reinterpret_cast<const f32x4*>(vbase + 4 * (g + 64));
    const f32x4 s4  = *reinterpret_cast<const f32x4*>(x1row + 4 * g);
    const f32x4 w0  = *reinterpret_cast<const f32x4*>(wrow +   0 + 4 * g);
    const f32x4 w1  = *reinterpret_cast<const f32x4*>(wrow + 128 + 4 * g);
    const f32x4 w2  = *reinterpret_cast<const f32x4*>(wrow + 256 + 4 * g);
    const f32x4 w3  = *reinterpret_cast<const f32x4*>(wrow + 384 + 4 * g);
    const f32x4 w4  = *reinterpret_cast<const f32x4*>(wrow + 512 + 4 * g);
    const f32x4 x2v = *reinterpret_cast<const f32x4*>(x2 + (size_t)z * 4);

    __builtin_amdgcn_sched_barrier(0);   // pin: all global loads issue first

    // ---- LDS transpose in: contiguous write, strided (conflict-light) read ----
    *reinterpret_cast<f32x4*>(buf + 4 * g)        = sv0;
    *reinterpret_cast<f32x4*>(buf + 4 * (g + 32)) = sv1;
    *reinterpret_cast<f32x4*>(buf + 4 * (g + 64)) = sv2;
    const f32x4 va = *reinterpret_cast<const f32x4*>(buf + 12 * g);
    const f32x4 vb = *reinterpret_cast<const f32x4*>(buf + 12 * g + 4);
    const f32x4 vc = *reinterpret_cast<const f32x4*>(buf + 12 * g + 8);

    // ---- compute ----
    const float a  = x2v.x;
    const float bx = x2v.y, by = x2v.z, bz = x2v.w;

    const float s[4]   = {s4.x, s4.y, s4.z, s4.w};
    const float vv[12] = {va.x, va.y, va.z, va.w,
                          vb.x, vb.y, vb.z, vb.w,
                          vc.x, vc.y, vc.z, vc.w};
    const float W0[4]  = {w0.x, w0.y, w0.z, w0.w};
    const float W1[4]  = {w1.x, w1.y, w1.z, w1.w};
    const float W2[4]  = {w2.x, w2.y, w2.z, w2.w};
    const float W3[4]  = {w3.x, w3.y, w3.z, w3.w};
    const float W4[4]  = {w4.x, w4.y, w4.z, w4.w};

    float os[4];
    float ov[12];
#pragma unroll
    for (int c = 0; c < 4; ++c) {
        const float vx = vv[3 * c + 0];
        const float vy = vv[3 * c + 1];
        const float vz = vv[3 * c + 2];
        const float dot = vx * bx + vy * by + vz * bz;
        os[c] = s[c] * a * W0[c] + inv_sqrt3 * dot * W3[c];

        const float cx = vy * bz - vz * by;   // v x b
        const float cy = vz * bx - vx * bz;
        const float cz = vx * by - vy * bx;

        const float t1 = inv_sqrt3 * s[c] * W1[c];
        const float t2 = inv_sqrt3 * a   * W2[c];
        const float t4 = inv_sqrt6 * W4[c];
        ov[3 * c + 0] = t1 * bx + t2 * vx + t4 * cx;
        ov[3 * c + 1] = t1 * by + t2 * vy + t4 * cy;
        ov[3 * c + 2] = t1 * bz + t2 * vz + t4 * cz;
    }

    // scalar output: already contiguous, store direct
    f32x4 o0 = {os[0], os[1], os[2], os[3]};
    *reinterpret_cast<f32x4*>(outrow + 4 * g) = o0;

    // ---- LDS transpose out: strided write, contiguous read-back + store ----
    // Same wave-lockstep buffer reuse: all lanes finished their strided reads
    // above before any lane executes these writes (in-order wave execution).
    f32x4 o1 = {ov[0], ov[1], ov[2],  ov[3]};
    f32x4 o2 = {ov[4], ov[5], ov[6],  ov[7]};
    f32x4 o3 = {ov[8], ov[9], ov[10], ov[11]};
    *reinterpret_cast<f32x4*>(buf + 12 * g)     = o1;
    *reinterpret_cast<f32x4*>(buf + 12 * g + 4) = o2;
    *reinterpret_cast<f32x4*>(buf + 12 * g + 8) = o3;
    const f32x4 r0 = *reinterpret_cast<const f32x4*>(buf + 4 * g);
    const f32x4 r1 = *reinterpret_cast<const f32x4*>(buf + 4 * (g + 32));
    const f32x4 r2 = *reinterpret_cast<const f32x4*>(buf + 4 * (g + 64));
    *reinterpret_cast<f32x4*>(outrow + 128 + 4 * g)        = r0;
    *reinterpret_cast<f32x4*>(outrow + 128 + 4 * (g + 32)) = r1;
    *reinterpret_cast<f32x4*>(outrow + 128 + 4 * (g + 64)) = r2;
}

extern "C" void kernel_launch(void* const* d_in, const int* in_sizes, int n_in,
                              void* d_out, int out_size, void* d_ws, size_t ws_size,
                              hipStream_t stream) {
    const float* x1 = (const float*)d_in[0];
    const float* x2 = (const float*)d_in[1];
    const float* w  = (const float*)d_in[2];
    float* out = (float*)d_out;

    const int n_edges = in_sizes[0] / 512;
    const long long total_threads = (long long)n_edges * 32;
    const int block = 256;
    const int grid = (int)((total_threads + block - 1) / block);

    tp_uvu_kernel<<<grid, block, 0, stream>>>(x1, x2, w, out, n_edges);
}